// Round 3
// baseline (59848.895 us; speedup 1.0000x reference)
//
#include <hip/hip_runtime.h>
#include <hip/hip_bf16.h>
#include <math.h>

// R18: stall elimination in the tiled convs, numerics BIT-IDENTICAL to R17.
//  - Double-buffered LDS staging with async split (load->regs BEFORE compute,
//    ds_write AFTER, one barrier/round) for all K>1 convs and both deconvs.
//    Staging mechanics only — per-output fmaf/fma chains unchanged.
//  - +1-element LDS row padding (RS=IT+1): odd-dword row stride spreads the
//    compute-phase ds_reads across 16 banks (was 4 -> ~4-way conflict, 1e7
//    conflict-cycles on enc2).
// Pipeline: fp64 encoder -> fp32 z, np-exact fp32 VQ, straight-through
// fl(z+fl(q-z)), fp32 decoder, fp32 output writes.

template<typename T> __device__ __forceinline__ T fmaT(T a, T b, T c);
template<> __device__ __forceinline__ double fmaT(double a, double b, double c) { return fma(a, b, c); }
template<> __device__ __forceinline__ float  fmaT(float a, float b, float c)    { return fmaf(a, b, c); }
template<typename T> __device__ __forceinline__ T maxT(T a, T b);
template<> __device__ __forceinline__ double maxT(double a, double b) { return fmax(a, b); }
template<> __device__ __forceinline__ float  maxT(float a, float b)   { return fmaxf(a, b); }

// ---------------------------------------------------------------------------
// LDS-tiled conv. 256 threads = 4 waves; 16x16 output tile x COB couts.
// DBUF: double-buffered staging, loads issued before compute (latency hidden
// under FMAs), ds_write after, 1 barrier/round. Rows padded (+1 elem).
// Accumulation per output: ci asc, kh asc, kw asc — bit-identical always.
// ---------------------------------------------------------------------------
template<typename TIn, typename TAcc, typename TOut, int K, int S, int PAD,
         bool IN_RELU, bool OUT_RELU, bool RES_ADD, int NCI, int COB, bool DBUF>
__global__ __launch_bounds__(256, 3)
void conv_tiled(const TIn* __restrict__ in, const float* __restrict__ w,
                const float* __restrict__ bias, const TAcc* __restrict__ res,
                TOut* __restrict__ out,
                int B, int Cin, int Hin, int Win, int Cout, int Hout, int Wout)
{
    constexpr int TILE = 16;
    constexpr int IT   = (TILE - 1) * S + K;   // input tile edge incl. halo
    constexpr int ITT  = IT * IT;
    constexpr int RS   = IT + 1;               // padded row stride (bank spread)
    constexpr int CSZ  = IT * RS;              // padded per-channel size
    constexpr int BUFSZ= NCI * CSZ;
    constexpr int NEL  = NCI * ITT;            // logical elements per stage
    constexpr int CEIL = (NEL + 255) / 256;
    constexpr int CPW  = COB / 4;
    constexpr int PIX  = 4;
    constexpr int WIN  = (PIX - 1) * S + K;

    __shared__ TAcc tile[(DBUF ? 2 : 1) * BUFSZ];

    int ntx = Wout / TILE, nty = Hout / TILE, ncb = Cout / COB;
    int g = blockIdx.x;
    int tx = g % ntx; g /= ntx;
    int ty = g % nty; g /= nty;
    int cb = g % ncb;
    int b  = g / ncb;

    int t    = threadIdx.x;
    int wave = t >> 6;
    int lowg = t & 3;
    int loh  = (t >> 2) & 15;
    int co0  = cb * COB + wave * CPW;
    int oh0t = ty * TILE, ow0t = tx * TILE;
    int oh   = oh0t + loh;
    int ow0  = ow0t + lowg * PIX;

    TAcc acc[CPW][PIX];
    #pragma unroll
    for (int c = 0; c < CPW; c++) {
        TAcc bv = (TAcc)bias[co0 + c];
        #pragma unroll
        for (int j = 0; j < PIX; j++) acc[c][j] = bv;
    }

    const int ihb = oh0t * S - PAD;
    const int iwb = ow0t * S - PAD;
    const long inHW = (long)Hin * Win;
    const int KK  = K * K;
    const int wCK = Cin * KK;

    auto stage_direct = [&](TAcc* dst, int ci0) {
        for (int e = t; e < NEL; e += 256) {
            int c = e / ITT, rm = e - c * ITT;
            int rr = rm / IT, cc = rm - rr * IT;
            int ih = ihb + rr, iw = iwb + cc;
            TAcc v = (TAcc)0;
            if ((unsigned)ih < (unsigned)Hin && (unsigned)iw < (unsigned)Win)
                v = (TAcc)in[((long)b * Cin + ci0 + c) * inHW + (long)ih * Win + iw];
            if (IN_RELU) v = maxT(v, (TAcc)0);
            dst[c * CSZ + rr * RS + cc] = v;
        }
    };

    auto compute = [&](const TAcc* tb, int ci0) {
        #pragma unroll
        for (int c = 0; c < NCI; c++) {
            const float* wp = w + ((long)co0 * Cin + (ci0 + c)) * KK;
            #pragma unroll
            for (int kh = 0; kh < K; kh++) {
                const TAcc* rp = tb + c * CSZ + (loh * S + kh) * RS + lowg * PIX * S;
                TAcc iv[WIN];
                #pragma unroll
                for (int x = 0; x < WIN; x++) iv[x] = rp[x];
                #pragma unroll
                for (int c2 = 0; c2 < CPW; c2++) {
                    #pragma unroll
                    for (int kw = 0; kw < K; kw++) {
                        TAcc wv = (TAcc)wp[c2 * wCK + kh * K + kw];
                        #pragma unroll
                        for (int j = 0; j < PIX; j++)
                            acc[c2][j] = fmaT(iv[j * S + kw], wv, acc[c2][j]);
                    }
                }
            }
        }
    };

    if constexpr (DBUF) {
        stage_direct(tile, 0);
        __syncthreads();
        const int ROUNDS = Cin / NCI;
        for (int r = 0; r < ROUNDS; r++) {
            TAcc regs[CEIL];
            const bool nxt = (r + 1 < ROUNDS);
            if (nxt) {
                int ci0n = (r + 1) * NCI;
                #pragma unroll
                for (int i = 0; i < CEIL; i++) {
                    int e = t + i * 256;
                    TAcc v = (TAcc)0;
                    if (e < NEL) {
                        int c = e / ITT, rm = e - c * ITT;
                        int rr = rm / IT, cc = rm - rr * IT;
                        int ih = ihb + rr, iw = iwb + cc;
                        if ((unsigned)ih < (unsigned)Hin && (unsigned)iw < (unsigned)Win)
                            v = (TAcc)in[((long)b * Cin + ci0n + c) * inHW + (long)ih * Win + iw];
                        if (IN_RELU) v = maxT(v, (TAcc)0);
                    }
                    regs[i] = v;
                }
            }
            compute(tile + (r & 1) * BUFSZ, r * NCI);
            if (nxt) {
                TAcc* dst = tile + ((r + 1) & 1) * BUFSZ;
                #pragma unroll
                for (int i = 0; i < CEIL; i++) {
                    int e = t + i * 256;
                    if (e < NEL) {
                        int c = e / ITT, rm = e - c * ITT;
                        int rr = rm / IT, cc = rm - rr * IT;
                        dst[c * CSZ + rr * RS + cc] = regs[i];
                    }
                }
                __syncthreads();
            }
        }
    } else {
        for (int ci0 = 0; ci0 < Cin; ci0 += NCI) {
            __syncthreads();
            stage_direct(tile, ci0);
            __syncthreads();
            compute(tile, ci0);
        }
    }

    long ostride = (long)Hout * Wout;
    long obase = (((long)b * Cout + co0) * Hout + oh) * Wout + ow0;
    #pragma unroll
    for (int c = 0; c < CPW; c++) {
        #pragma unroll
        for (int j = 0; j < PIX; j++) {
            TAcc v = acc[c][j];
            if (RES_ADD) v += res[obase + c * ostride + j];
            if (OUT_RELU) v = maxT(v, (TAcc)0);
            out[obase + c * ostride + j] = (TOut)v;
        }
    }
}

// ---------------------------------------------------------------------------
// LDS-tiled ConvTranspose2d k=4 s=2 p=1, fp32, double-buffered staging.
// Each thread owns input pos (tiy,tix) of a 16x16 tile (18x18 halo in LDS,
// padded rows) and computes its 2x2 output quad for CQ couts. Per-output
// fmaf chains replicate the original deconv exactly (see R17 comment).
// ---------------------------------------------------------------------------
template<int CQ, bool IN_RELU, bool OUT_RELU, bool OUT_TANH, int NCI>
__global__ __launch_bounds__(256, 3)
void deconv_tiled(const float* __restrict__ in, const float* __restrict__ w,
                  const float* __restrict__ bias, float* __restrict__ out,
                  int B, int Cin, int Hin, int Win, int Cout)
{
    constexpr int IT  = 18;          // 16 + 2 halo
    constexpr int ITT = IT * IT;
    constexpr int RS  = IT + 1;
    constexpr int CSZ = IT * RS;
    constexpr int BUFSZ = NCI * CSZ;
    constexpr int NEL = NCI * ITT;
    constexpr int CEIL = (NEL + 255) / 256;
    int Hout = Hin << 1, Wout = Win << 1;

    __shared__ float tile[2 * BUFSZ];

    int ntx = Win >> 4, nty = Hin >> 4, ncb = Cout / CQ;
    int g = blockIdx.x;
    int tx = g % ntx; g /= ntx;
    int ty = g % nty; g /= nty;
    int cb = g % ncb;
    int b  = g / ncb;

    int t   = threadIdx.x;
    int tix = t & 15;
    int tiy = t >> 4;
    int ix0 = tx << 4, iy0 = ty << 4;
    int co0 = cb * CQ;

    float acc[CQ][4];
    #pragma unroll
    for (int c = 0; c < CQ; c++) {
        float bv = bias[co0 + c];
        #pragma unroll
        for (int j = 0; j < 4; j++) acc[c][j] = bv;
    }

    const long inHW = (long)Hin * Win;

    auto stage_direct = [&](float* dst, int ci0) {
        for (int e = t; e < NEL; e += 256) {
            int c = e / ITT, rm = e - c * ITT;
            int rr = rm / IT, cc = rm - rr * IT;
            int ih = iy0 - 1 + rr, iw = ix0 - 1 + cc;
            float v = 0.f;
            if ((unsigned)ih < (unsigned)Hin && (unsigned)iw < (unsigned)Win)
                v = in[((long)b * Cin + ci0 + c) * inHW + (long)ih * Win + iw];
            if (IN_RELU) v = fmaxf(v, 0.f);
            dst[c * CSZ + rr * RS + cc] = v;
        }
    };

    auto compute = [&](const float* tb, int ci0) {
        #pragma unroll
        for (int c = 0; c < NCI; c++) {
            const float* tp = tb + c * CSZ + tiy * RS + tix;
            float n00 = tp[0],        n01 = tp[1],          n02 = tp[2];
            float n10 = tp[RS],       n11 = tp[RS + 1],     n12 = tp[RS + 2];
            float n20 = tp[2 * RS],   n21 = tp[2 * RS + 1], n22 = tp[2 * RS + 2];
            const float* wb = w + ((long)(ci0 + c) * Cout + co0) * 16;
            #pragma unroll
            for (int cq = 0; cq < CQ; cq++) {
                const float* wk = wb + cq * 16;
                float a0 = acc[cq][0], a1 = acc[cq][1];
                float a2 = acc[cq][2], a3 = acc[cq][3];
                a0 = fmaf(n11, wk[5],  fmaf(n10, wk[7],  a0));
                a0 = fmaf(n01, wk[13], fmaf(n00, wk[15], a0));
                a1 = fmaf(n12, wk[4],  fmaf(n11, wk[6],  a1));
                a1 = fmaf(n02, wk[12], fmaf(n01, wk[14], a1));
                a2 = fmaf(n21, wk[1],  fmaf(n20, wk[3],  a2));
                a2 = fmaf(n11, wk[9],  fmaf(n10, wk[11], a2));
                a3 = fmaf(n22, wk[0],  fmaf(n21, wk[2],  a3));
                a3 = fmaf(n12, wk[8],  fmaf(n11, wk[10], a3));
                acc[cq][0] = a0; acc[cq][1] = a1;
                acc[cq][2] = a2; acc[cq][3] = a3;
            }
        }
    };

    stage_direct(tile, 0);
    __syncthreads();
    const int ROUNDS = Cin / NCI;
    for (int r = 0; r < ROUNDS; r++) {
        float regs[CEIL];
        const bool nxt = (r + 1 < ROUNDS);
        if (nxt) {
            int ci0n = (r + 1) * NCI;
            #pragma unroll
            for (int i = 0; i < CEIL; i++) {
                int e = t + i * 256;
                float v = 0.f;
                if (e < NEL) {
                    int c = e / ITT, rm = e - c * ITT;
                    int rr = rm / IT, cc = rm - rr * IT;
                    int ih = iy0 - 1 + rr, iw = ix0 - 1 + cc;
                    if ((unsigned)ih < (unsigned)Hin && (unsigned)iw < (unsigned)Win)
                        v = in[((long)b * Cin + ci0n + c) * inHW + (long)ih * Win + iw];
                    if (IN_RELU) v = fmaxf(v, 0.f);
                }
                regs[i] = v;
            }
        }
        compute(tile + (r & 1) * BUFSZ, r * NCI);
        if (nxt) {
            float* dst = tile + ((r + 1) & 1) * BUFSZ;
            #pragma unroll
            for (int i = 0; i < CEIL; i++) {
                int e = t + i * 256;
                if (e < NEL) {
                    int c = e / ITT, rm = e - c * ITT;
                    int rr = rm / IT, cc = rm - rr * IT;
                    dst[c * CSZ + rr * RS + cc] = regs[i];
                }
            }
            __syncthreads();
        }
    }

    int oh0 = (iy0 + tiy) << 1;
    int ow0 = (ix0 + tix) << 1;
    long ostride = (long)Hout * Wout;
    long obase = (((long)b * Cout + co0) * Hout + oh0) * Wout + ow0;
    #pragma unroll
    for (int c = 0; c < CQ; c++) {
        #pragma unroll
        for (int j = 0; j < 4; j++) {
            float v = acc[c][j];
            if (OUT_RELU) v = fmaxf(v, 0.f);
            if (OUT_TANH) v = tanhf(v);
            out[obase + c * ostride + (j >> 1) * (long)Wout + (j & 1)] = v;
        }
    }
}

// numpy pairwise sum-of-squares over 64 fp32 values.
__device__ __forceinline__ float np_sumsq64(const float* v) {
    float r[8];
    #pragma unroll
    for (int j = 0; j < 8; j++) r[j] = __fmul_rn(v[j], v[j]);
    #pragma unroll
    for (int i = 8; i < 64; i += 8) {
        #pragma unroll
        for (int j = 0; j < 8; j++)
            r[j] = __fadd_rn(r[j], __fmul_rn(v[i + j], v[i + j]));
    }
    float s01 = __fadd_rn(r[0], r[1]), s23 = __fadd_rn(r[2], r[3]);
    float s45 = __fadd_rn(r[4], r[5]), s67 = __fadd_rn(r[6], r[7]);
    return __fadd_rn(__fadd_rn(s01, s23), __fadd_rn(s45, s67));
}

__global__ void codenorm_kernel(const float* __restrict__ cb, float* __restrict__ cn)
{
    int k = blockIdx.x * 64 + threadIdx.x;
    if (k >= 512) return;
    float row[64];
    #pragma unroll
    for (int d = 0; d < 64; d++) row[d] = cb[k * 64 + d];
    cn[k] = np_sumsq64(row);
}

// VQ: np-exact fp32 chain; st = fl(z + fl(q-z)).
__global__ __launch_bounds__(256)
void vq_kernel(const float* __restrict__ z, const float* __restrict__ cb,
               const float* __restrict__ cn, float* __restrict__ st,
               double* __restrict__ loss_sum, int B)
{
    __shared__ float zt[64][256];
    int t = threadIdx.x;
    long pg = (long)blockIdx.x * 256;
    int b = (int)(pg >> 12);
    int p0 = (int)(pg & 4095);
    const float* zb = z + (long)b * 64 * 4096 + p0;
    #pragma unroll
    for (int d = 0; d < 64; d++) zt[d][t] = zb[(long)d * 4096 + t];
    __syncthreads();

    int p = p0 + t;
    float zr[64];
    #pragma unroll
    for (int d = 0; d < 64; d++) zr[d] = zt[d][t];

    float s1 = np_sumsq64(zr);

    float best = INFINITY;
    int bi = 0;
    for (int k = 0; k < 512; k += 4) {
        const float* c0 = cb + (k + 0) * 64;
        const float* c1 = cb + (k + 1) * 64;
        const float* c2 = cb + (k + 2) * 64;
        const float* c3 = cb + (k + 3) * 64;
        float m0 = 0.f, m1 = 0.f, m2 = 0.f, m3 = 0.f;
        #pragma unroll
        for (int d = 0; d < 64; d++) {
            float zd = zr[d];
            m0 = fmaf(zd, c0[d], m0);
            m1 = fmaf(zd, c1[d], m1);
            m2 = fmaf(zd, c2[d], m2);
            m3 = fmaf(zd, c3[d], m3);
        }
        float d0 = __fadd_rn(__fsub_rn(s1, __fmul_rn(2.f, m0)), cn[k + 0]);
        float d1 = __fadd_rn(__fsub_rn(s1, __fmul_rn(2.f, m1)), cn[k + 1]);
        float d2 = __fadd_rn(__fsub_rn(s1, __fmul_rn(2.f, m2)), cn[k + 2]);
        float d3 = __fadd_rn(__fsub_rn(s1, __fmul_rn(2.f, m3)), cn[k + 3]);
        if (d0 < best) { best = d0; bi = k + 0; }
        if (d1 < best) { best = d1; bi = k + 1; }
        if (d2 < best) { best = d2; bi = k + 2; }
        if (d3 < best) { best = d3; bi = k + 3; }
    }

    const float* cbest = cb + bi * 64;
    float* sp = st + (long)b * 64 * 4096 + p;
    double ls = 0.0;
    #pragma unroll
    for (int d = 0; d < 64; d++) {
        float qv = cbest[d];
        float zv = zr[d];
        float diff = __fsub_rn(qv, zv);
        double dd = (double)qv - (double)zv;
        ls += dd * dd;
        sp[(long)d * 4096] = __fadd_rn(zv, diff);
    }
    #pragma unroll
    for (int off = 32; off > 0; off >>= 1) ls += __shfl_down(ls, off, 64);
    if ((t & 63) == 0) atomicAdd(loss_sum, ls);
}

__global__ void loss_final_kernel(const double* __restrict__ s, float* __restrict__ out)
{
    out[0] = (float)(1.25 * s[0] / 8388608.0);   // fp32 loss store
}

extern "C" void kernel_launch(void* const* d_in, const int* in_sizes, int n_in,
                              void* d_out, int out_size, void* d_ws, size_t ws_size,
                              hipStream_t stream)
{
    const float* x        = (const float*)d_in[0];
    const float* enc_w1   = (const float*)d_in[1];
    const float* enc_b1   = (const float*)d_in[2];
    const float* enc_w2   = (const float*)d_in[3];
    const float* enc_b2   = (const float*)d_in[4];
    const float* enc_w3   = (const float*)d_in[5];
    const float* enc_b3   = (const float*)d_in[6];
    const float* enc_rw1  = (const float*)d_in[7];
    const float* enc_rb1  = (const float*)d_in[8];
    const float* enc_rw2  = (const float*)d_in[9];
    const float* enc_rb2  = (const float*)d_in[10];
    const float* pvq_w    = (const float*)d_in[11];
    const float* pvq_b    = (const float*)d_in[12];
    const float* codebook = (const float*)d_in[13];
    const float* dec_w1   = (const float*)d_in[14];
    const float* dec_b1   = (const float*)d_in[15];
    const float* dec_rw1  = (const float*)d_in[16];
    const float* dec_rb1  = (const float*)d_in[17];
    const float* dec_rw2  = (const float*)d_in[18];
    const float* dec_rb2  = (const float*)d_in[19];
    const float* dt1_w    = (const float*)d_in[20];
    const float* dt1_b    = (const float*)d_in[21];
    const float* dt2_w    = (const float*)d_in[22];
    const float* dt2_b    = (const float*)d_in[23];

    float* out = (float*)d_out;            // fp32 output buffer (ref dtype)
    char* wsb = (char*)d_ws;

    float*  CN = (float*)wsb;              // 512 floats
    double* LS = (double*)(wsb + 4096);    // 1 double
    const size_t SMALLB = 4352;

    const long eA = 1048576, eB = 524288, eC = 524288, eT = 131072;
    const long eZ = 262144, eQ = 262144;
    const size_t perSampleB = (size_t)(eA + eB + eC + eT) * 8 + (size_t)(eZ + eQ) * 4;

    int Bc = 32;
    while (Bc > 1 && SMALLB + perSampleB * Bc + 1024 > ws_size) Bc >>= 1;
    const int nChunks = 32 / Bc;

    double* A64 = (double*)(wsb + SMALLB);
    double* B64 = A64 + eA * Bc;
    double* C64 = B64 + eB * Bc;
    double* T64 = C64 + eC * Bc;
    float*  Z32 = (float*)(T64 + eT * Bc);
    float*  Qf  = Z32 + eZ * Bc;
    float* Df = (float*)B64;   // decoder fp32 aliases (encoder buffers dead)
    float* Tf = (float*)T64;
    float* Ef = (float*)A64;

    hipMemsetAsync(LS, 0, sizeof(double), stream);
    codenorm_kernel<<<8, 64, 0, stream>>>(codebook, CN);

    for (int c = 0; c < nChunks; c++) {
        const float* xc = x + (long)c * Bc * 3 * 65536;
        float* outc = out + (long)c * Bc * 3 * 65536;

        // ---- encoder (fp64 accumulate -> fp32 z) ----
        // enc1: 4x4 s2 3->64, 256->128, OUT_RELU. Cin=3=NCI: single round.
        conv_tiled<float,double,double,4,2,1,false,true,false,3,32,false>
            <<<Bc*8*8*2, 256, 0, stream>>>(
            xc, enc_w1, enc_b1, nullptr, A64, Bc, 3, 256, 256, 64, 128, 128);
        // enc2: 4x4 s2 64->128, 128->64, OUT_RELU. DBUF.
        conv_tiled<double,double,double,4,2,1,false,true,false,2,32,true>
            <<<Bc*4*4*4, 256, 0, stream>>>(
            A64, enc_w2, enc_b2, nullptr, B64, Bc, 64, 128, 128, 128, 64, 64);
        // enc3: 3x3 s1 128->128. DBUF.
        conv_tiled<double,double,double,3,1,1,false,false,false,4,32,true>
            <<<Bc*4*4*4, 256, 0, stream>>>(
            B64, enc_w3, enc_b3, nullptr, C64, Bc, 128, 64, 64, 128, 64, 64);
        for (int i = 0; i < 2; i++) {
            // res1: 3x3 128->32, IN_RELU. COB=16. DBUF.
            conv_tiled<double,double,double,3,1,1,true,false,false,4,16,true>
                <<<Bc*4*4*2, 256, 0, stream>>>(
                C64, enc_rw1 + (long)i*32*128*9, enc_rb1 + i*32, nullptr, T64,
                Bc, 128, 64, 64, 32, 64, 64);
            // res2: 1x1 32->128, IN_RELU, +residual C64, in-place C64.
            conv_tiled<double,double,double,1,1,0,true,false,true,16,32,false>
                <<<Bc*4*4*4, 256, 0, stream>>>(
                T64, enc_rw2 + (long)i*128*32, enc_rb2 + i*128, C64, C64,
                Bc, 32, 64, 64, 128, 64, 64);
        }
        // pvq: 1x1 128->64, IN_RELU, fp32 store.
        conv_tiled<double,double,float,1,1,0,true,false,false,16,32,false>
            <<<Bc*4*4*2, 256, 0, stream>>>(
            C64, pvq_w, pvq_b, nullptr, Z32, Bc, 128, 64, 64, 64, 64, 64);

        // ---- VQ (np-exact fp32) ----
        vq_kernel<<<Bc * 16, 256, 0, stream>>>(Z32, codebook, CN, Qf, LS, Bc);

        // ---- decoder (fp32), fp32 output stores ----
        conv_tiled<float,float,float,3,1,1,false,false,false,8,32,true>
            <<<Bc*4*4*4, 256, 0, stream>>>(
            Qf, dec_w1, dec_b1, nullptr, Df, Bc, 64, 64, 64, 128, 64, 64);
        for (int i = 0; i < 2; i++) {
            conv_tiled<float,float,float,3,1,1,true,false,false,8,16,true>
                <<<Bc*4*4*2, 256, 0, stream>>>(
                Df, dec_rw1 + (long)i*32*128*9, dec_rb1 + i*32, nullptr, Tf,
                Bc, 128, 64, 64, 32, 64, 64);
            conv_tiled<float,float,float,1,1,0,true,false,true,16,32,false>
                <<<Bc*4*4*4, 256, 0, stream>>>(
                Tf, dec_rw2 + (long)i*128*32, dec_rb2 + i*128, Df, Df,
                Bc, 32, 64, 64, 128, 64, 64);
        }
        // dt1: deconv 128->64, 64->128, IN_RELU + OUT_RELU.
        deconv_tiled<8,true,true,false,8><<<Bc*4*4*8, 256, 0, stream>>>(
            Df, dt1_w, dt1_b, Ef, Bc, 128, 64, 64, 64);
        // dt2: deconv 64->3, 128->256, tanh, writes final output.
        deconv_tiled<3,false,false,true,8><<<Bc*8*8*1, 256, 0, stream>>>(
            Ef, dt2_w, dt2_b, outc, Bc, 64, 128, 128, 3);
    }

    loss_final_kernel<<<1, 1, 0, stream>>>(LS, out + 6291456);
}

// Round 4
// 9255.737 us; speedup vs baseline: 6.4661x; 6.4661x over previous
//
#include <hip/hip_runtime.h>
#include <hip/hip_bf16.h>
#include <math.h>

// R19: recover from R18's spill catastrophe. Numerics BIT-IDENTICAL to R17.
// R18 post-mortem: register-held prefetch arrays (regs[CEIL]) live across the
// fp64 compute (64 VGPR acc) spilled to scratch -> GB-scale FETCH/WRITE per
// dispatch, 7x regression. DBUF removed entirely.
// Kept from the R18 plan (both spill-free):
//  - +1-element LDS row padding (RS=IT+1): R17 enc2 had 1.05e7 bank-conflict
//    cycles (~4-way on ds_read_b64, row stride 68 dwords = 4 mod 32). Padded
//    stride spreads 16 rows across 16 banks, <=2 lanes/bank (2-way is free).
//  - Larger NCI (fewer stage rounds => fewer exposed-latency phases):
//    enc2 2->4, enc3/enc-res1 4->8, dec convs 8->16, deconvs 8->16.
// Pipeline: fp64 encoder -> fp32 z, np-exact fp32 VQ, straight-through
// fl(z+fl(q-z)), fp32 decoder, fp32 output writes.

template<typename T> __device__ __forceinline__ T fmaT(T a, T b, T c);
template<> __device__ __forceinline__ double fmaT(double a, double b, double c) { return fma(a, b, c); }
template<> __device__ __forceinline__ float  fmaT(float a, float b, float c)    { return fmaf(a, b, c); }
template<typename T> __device__ __forceinline__ T maxT(T a, T b);
template<> __device__ __forceinline__ double maxT(double a, double b) { return fmax(a, b); }
template<> __device__ __forceinline__ float  maxT(float a, float b)   { return fmaxf(a, b); }

// ---------------------------------------------------------------------------
// LDS-tiled conv. 256 threads = 4 waves; 16x16 output tile x COB couts.
// Single-buffer stage -> barrier -> compute (R17 structure). Rows padded +1.
// Accumulation per output: ci asc, kh asc, kw asc — bit-identical to direct.
// ---------------------------------------------------------------------------
template<typename TIn, typename TAcc, typename TOut, int K, int S, int PAD,
         bool IN_RELU, bool OUT_RELU, bool RES_ADD, int NCI, int COB>
__global__ __launch_bounds__(256, 3)
void conv_tiled(const TIn* __restrict__ in, const float* __restrict__ w,
                const float* __restrict__ bias, const TAcc* __restrict__ res,
                TOut* __restrict__ out,
                int B, int Cin, int Hin, int Win, int Cout, int Hout, int Wout)
{
    constexpr int TILE = 16;
    constexpr int IT   = (TILE - 1) * S + K;   // input tile edge incl. halo
    constexpr int ITT  = IT * IT;
    constexpr int RS   = IT + 1;               // padded row stride (bank spread)
    constexpr int CSZ  = IT * RS;              // padded per-channel size
    constexpr int NEL  = NCI * ITT;            // logical elements per stage
    constexpr int CPW  = COB / 4;
    constexpr int PIX  = 4;
    constexpr int WIN  = (PIX - 1) * S + K;

    __shared__ TAcc tile[NCI * CSZ];

    int ntx = Wout / TILE, nty = Hout / TILE, ncb = Cout / COB;
    int g = blockIdx.x;
    int tx = g % ntx; g /= ntx;
    int ty = g % nty; g /= nty;
    int cb = g % ncb;
    int b  = g / ncb;

    int t    = threadIdx.x;
    int wave = t >> 6;
    int lowg = t & 3;
    int loh  = (t >> 2) & 15;
    int co0  = cb * COB + wave * CPW;
    int oh0t = ty * TILE, ow0t = tx * TILE;
    int oh   = oh0t + loh;
    int ow0  = ow0t + lowg * PIX;

    TAcc acc[CPW][PIX];
    #pragma unroll
    for (int c = 0; c < CPW; c++) {
        TAcc bv = (TAcc)bias[co0 + c];
        #pragma unroll
        for (int j = 0; j < PIX; j++) acc[c][j] = bv;
    }

    const int ihb = oh0t * S - PAD;
    const int iwb = ow0t * S - PAD;
    const long inHW = (long)Hin * Win;
    const int KK  = K * K;
    const int wCK = Cin * KK;

    for (int ci0 = 0; ci0 < Cin; ci0 += NCI) {
        __syncthreads();
        for (int e = t; e < NEL; e += 256) {
            int c = e / ITT, rm = e - c * ITT;
            int rr = rm / IT, cc = rm - rr * IT;
            int ih = ihb + rr, iw = iwb + cc;
            TAcc v = (TAcc)0;
            if ((unsigned)ih < (unsigned)Hin && (unsigned)iw < (unsigned)Win)
                v = (TAcc)in[((long)b * Cin + ci0 + c) * inHW + (long)ih * Win + iw];
            if (IN_RELU) v = maxT(v, (TAcc)0);
            tile[c * CSZ + rr * RS + cc] = v;
        }
        __syncthreads();
        #pragma unroll
        for (int c = 0; c < NCI; c++) {
            const float* wp = w + ((long)co0 * Cin + (ci0 + c)) * KK;
            #pragma unroll
            for (int kh = 0; kh < K; kh++) {
                const TAcc* rp = tile + c * CSZ + (loh * S + kh) * RS + lowg * PIX * S;
                TAcc iv[WIN];
                #pragma unroll
                for (int x = 0; x < WIN; x++) iv[x] = rp[x];
                #pragma unroll
                for (int c2 = 0; c2 < CPW; c2++) {
                    #pragma unroll
                    for (int kw = 0; kw < K; kw++) {
                        TAcc wv = (TAcc)wp[c2 * wCK + kh * K + kw];
                        #pragma unroll
                        for (int j = 0; j < PIX; j++)
                            acc[c2][j] = fmaT(iv[j * S + kw], wv, acc[c2][j]);
                    }
                }
            }
        }
    }

    long ostride = (long)Hout * Wout;
    long obase = (((long)b * Cout + co0) * Hout + oh) * Wout + ow0;
    #pragma unroll
    for (int c = 0; c < CPW; c++) {
        #pragma unroll
        for (int j = 0; j < PIX; j++) {
            TAcc v = acc[c][j];
            if (RES_ADD) v += res[obase + c * ostride + j];
            if (OUT_RELU) v = maxT(v, (TAcc)0);
            out[obase + c * ostride + j] = (TOut)v;
        }
    }
}

// ---------------------------------------------------------------------------
// LDS-tiled ConvTranspose2d k=4 s=2 p=1, fp32, single-buffer staging.
// Each thread owns input pos (tiy,tix) of a 16x16 tile (18x18 halo in LDS,
// padded rows) and computes its 2x2 output quad for CQ couts. Per-output
// fmaf chains replicate the original deconv exactly:
//   even oh: kh=1 (row iy) then kh=3 (row iy-1); odd oh: kh=0 (iy+1), kh=2 (iy)
//   even ow: +i[iw-1]*w[kh][3] then +i[iw]*w[kh][1]
//   odd  ow: +i[iw]*w[kh][2]  then +i[iw+1]*w[kh][0]
// ---------------------------------------------------------------------------
template<int CQ, bool IN_RELU, bool OUT_RELU, bool OUT_TANH, int NCI>
__global__ __launch_bounds__(256, 3)
void deconv_tiled(const float* __restrict__ in, const float* __restrict__ w,
                  const float* __restrict__ bias, float* __restrict__ out,
                  int B, int Cin, int Hin, int Win, int Cout)
{
    constexpr int IT  = 18;          // 16 + 2 halo
    constexpr int ITT = IT * IT;
    constexpr int RS  = IT + 1;
    constexpr int CSZ = IT * RS;
    constexpr int NEL = NCI * ITT;
    int Hout = Hin << 1, Wout = Win << 1;

    __shared__ float tile[NCI * CSZ];

    int ntx = Win >> 4, nty = Hin >> 4, ncb = Cout / CQ;
    int g = blockIdx.x;
    int tx = g % ntx; g /= ntx;
    int ty = g % nty; g /= nty;
    int cb = g % ncb;
    int b  = g / ncb;

    int t   = threadIdx.x;
    int tix = t & 15;
    int tiy = t >> 4;
    int ix0 = tx << 4, iy0 = ty << 4;
    int co0 = cb * CQ;

    float acc[CQ][4];
    #pragma unroll
    for (int c = 0; c < CQ; c++) {
        float bv = bias[co0 + c];
        #pragma unroll
        for (int j = 0; j < 4; j++) acc[c][j] = bv;
    }

    const long inHW = (long)Hin * Win;

    for (int ci0 = 0; ci0 < Cin; ci0 += NCI) {
        __syncthreads();
        for (int e = t; e < NEL; e += 256) {
            int c = e / ITT, rm = e - c * ITT;
            int rr = rm / IT, cc = rm - rr * IT;
            int ih = iy0 - 1 + rr, iw = ix0 - 1 + cc;
            float v = 0.f;
            if ((unsigned)ih < (unsigned)Hin && (unsigned)iw < (unsigned)Win)
                v = in[((long)b * Cin + ci0 + c) * inHW + (long)ih * Win + iw];
            if (IN_RELU) v = fmaxf(v, 0.f);
            tile[c * CSZ + rr * RS + cc] = v;
        }
        __syncthreads();
        #pragma unroll
        for (int c = 0; c < NCI; c++) {
            const float* tp = tile + c * CSZ + tiy * RS + tix;
            float n00 = tp[0],        n01 = tp[1],          n02 = tp[2];
            float n10 = tp[RS],       n11 = tp[RS + 1],     n12 = tp[RS + 2];
            float n20 = tp[2 * RS],   n21 = tp[2 * RS + 1], n22 = tp[2 * RS + 2];
            const float* wb = w + ((long)(ci0 + c) * Cout + co0) * 16;
            #pragma unroll
            for (int cq = 0; cq < CQ; cq++) {
                const float* wk = wb + cq * 16;
                float a0 = acc[cq][0], a1 = acc[cq][1];
                float a2 = acc[cq][2], a3 = acc[cq][3];
                a0 = fmaf(n11, wk[5],  fmaf(n10, wk[7],  a0));
                a0 = fmaf(n01, wk[13], fmaf(n00, wk[15], a0));
                a1 = fmaf(n12, wk[4],  fmaf(n11, wk[6],  a1));
                a1 = fmaf(n02, wk[12], fmaf(n01, wk[14], a1));
                a2 = fmaf(n21, wk[1],  fmaf(n20, wk[3],  a2));
                a2 = fmaf(n11, wk[9],  fmaf(n10, wk[11], a2));
                a3 = fmaf(n22, wk[0],  fmaf(n21, wk[2],  a3));
                a3 = fmaf(n12, wk[8],  fmaf(n11, wk[10], a3));
                acc[cq][0] = a0; acc[cq][1] = a1;
                acc[cq][2] = a2; acc[cq][3] = a3;
            }
        }
    }

    int oh0 = (iy0 + tiy) << 1;
    int ow0 = (ix0 + tix) << 1;
    long ostride = (long)Hout * Wout;
    long obase = (((long)b * Cout + co0) * Hout + oh0) * Wout + ow0;
    #pragma unroll
    for (int c = 0; c < CQ; c++) {
        #pragma unroll
        for (int j = 0; j < 4; j++) {
            float v = acc[c][j];
            if (OUT_RELU) v = fmaxf(v, 0.f);
            if (OUT_TANH) v = tanhf(v);
            out[obase + c * ostride + (j >> 1) * (long)Wout + (j & 1)] = v;
        }
    }
}

// numpy pairwise sum-of-squares over 64 fp32 values.
__device__ __forceinline__ float np_sumsq64(const float* v) {
    float r[8];
    #pragma unroll
    for (int j = 0; j < 8; j++) r[j] = __fmul_rn(v[j], v[j]);
    #pragma unroll
    for (int i = 8; i < 64; i += 8) {
        #pragma unroll
        for (int j = 0; j < 8; j++)
            r[j] = __fadd_rn(r[j], __fmul_rn(v[i + j], v[i + j]));
    }
    float s01 = __fadd_rn(r[0], r[1]), s23 = __fadd_rn(r[2], r[3]);
    float s45 = __fadd_rn(r[4], r[5]), s67 = __fadd_rn(r[6], r[7]);
    return __fadd_rn(__fadd_rn(s01, s23), __fadd_rn(s45, s67));
}

__global__ void codenorm_kernel(const float* __restrict__ cb, float* __restrict__ cn)
{
    int k = blockIdx.x * 64 + threadIdx.x;
    if (k >= 512) return;
    float row[64];
    #pragma unroll
    for (int d = 0; d < 64; d++) row[d] = cb[k * 64 + d];
    cn[k] = np_sumsq64(row);
}

// VQ: np-exact fp32 chain; st = fl(z + fl(q-z)).
__global__ __launch_bounds__(256)
void vq_kernel(const float* __restrict__ z, const float* __restrict__ cb,
               const float* __restrict__ cn, float* __restrict__ st,
               double* __restrict__ loss_sum, int B)
{
    __shared__ float zt[64][256];
    int t = threadIdx.x;
    long pg = (long)blockIdx.x * 256;
    int b = (int)(pg >> 12);
    int p0 = (int)(pg & 4095);
    const float* zb = z + (long)b * 64 * 4096 + p0;
    #pragma unroll
    for (int d = 0; d < 64; d++) zt[d][t] = zb[(long)d * 4096 + t];
    __syncthreads();

    int p = p0 + t;
    float zr[64];
    #pragma unroll
    for (int d = 0; d < 64; d++) zr[d] = zt[d][t];

    float s1 = np_sumsq64(zr);

    float best = INFINITY;
    int bi = 0;
    for (int k = 0; k < 512; k += 4) {
        const float* c0 = cb + (k + 0) * 64;
        const float* c1 = cb + (k + 1) * 64;
        const float* c2 = cb + (k + 2) * 64;
        const float* c3 = cb + (k + 3) * 64;
        float m0 = 0.f, m1 = 0.f, m2 = 0.f, m3 = 0.f;
        #pragma unroll
        for (int d = 0; d < 64; d++) {
            float zd = zr[d];
            m0 = fmaf(zd, c0[d], m0);
            m1 = fmaf(zd, c1[d], m1);
            m2 = fmaf(zd, c2[d], m2);
            m3 = fmaf(zd, c3[d], m3);
        }
        float d0 = __fadd_rn(__fsub_rn(s1, __fmul_rn(2.f, m0)), cn[k + 0]);
        float d1 = __fadd_rn(__fsub_rn(s1, __fmul_rn(2.f, m1)), cn[k + 1]);
        float d2 = __fadd_rn(__fsub_rn(s1, __fmul_rn(2.f, m2)), cn[k + 2]);
        float d3 = __fadd_rn(__fsub_rn(s1, __fmul_rn(2.f, m3)), cn[k + 3]);
        if (d0 < best) { best = d0; bi = k + 0; }
        if (d1 < best) { best = d1; bi = k + 1; }
        if (d2 < best) { best = d2; bi = k + 2; }
        if (d3 < best) { best = d3; bi = k + 3; }
    }

    const float* cbest = cb + bi * 64;
    float* sp = st + (long)b * 64 * 4096 + p;
    double ls = 0.0;
    #pragma unroll
    for (int d = 0; d < 64; d++) {
        float qv = cbest[d];
        float zv = zr[d];
        float diff = __fsub_rn(qv, zv);
        double dd = (double)qv - (double)zv;
        ls += dd * dd;
        sp[(long)d * 4096] = __fadd_rn(zv, diff);
    }
    #pragma unroll
    for (int off = 32; off > 0; off >>= 1) ls += __shfl_down(ls, off, 64);
    if ((t & 63) == 0) atomicAdd(loss_sum, ls);
}

__global__ void loss_final_kernel(const double* __restrict__ s, float* __restrict__ out)
{
    out[0] = (float)(1.25 * s[0] / 8388608.0);   // fp32 loss store
}

extern "C" void kernel_launch(void* const* d_in, const int* in_sizes, int n_in,
                              void* d_out, int out_size, void* d_ws, size_t ws_size,
                              hipStream_t stream)
{
    const float* x        = (const float*)d_in[0];
    const float* enc_w1   = (const float*)d_in[1];
    const float* enc_b1   = (const float*)d_in[2];
    const float* enc_w2   = (const float*)d_in[3];
    const float* enc_b2   = (const float*)d_in[4];
    const float* enc_w3   = (const float*)d_in[5];
    const float* enc_b3   = (const float*)d_in[6];
    const float* enc_rw1  = (const float*)d_in[7];
    const float* enc_rb1  = (const float*)d_in[8];
    const float* enc_rw2  = (const float*)d_in[9];
    const float* enc_rb2  = (const float*)d_in[10];
    const float* pvq_w    = (const float*)d_in[11];
    const float* pvq_b    = (const float*)d_in[12];
    const float* codebook = (const float*)d_in[13];
    const float* dec_w1   = (const float*)d_in[14];
    const float* dec_b1   = (const float*)d_in[15];
    const float* dec_rw1  = (const float*)d_in[16];
    const float* dec_rb1  = (const float*)d_in[17];
    const float* dec_rw2  = (const float*)d_in[18];
    const float* dec_rb2  = (const float*)d_in[19];
    const float* dt1_w    = (const float*)d_in[20];
    const float* dt1_b    = (const float*)d_in[21];
    const float* dt2_w    = (const float*)d_in[22];
    const float* dt2_b    = (const float*)d_in[23];

    float* out = (float*)d_out;            // fp32 output buffer (ref dtype)
    char* wsb = (char*)d_ws;

    float*  CN = (float*)wsb;              // 512 floats
    double* LS = (double*)(wsb + 4096);    // 1 double
    const size_t SMALLB = 4352;

    const long eA = 1048576, eB = 524288, eC = 524288, eT = 131072;
    const long eZ = 262144, eQ = 262144;
    const size_t perSampleB = (size_t)(eA + eB + eC + eT) * 8 + (size_t)(eZ + eQ) * 4;

    int Bc = 32;
    while (Bc > 1 && SMALLB + perSampleB * Bc + 1024 > ws_size) Bc >>= 1;
    const int nChunks = 32 / Bc;

    double* A64 = (double*)(wsb + SMALLB);
    double* B64 = A64 + eA * Bc;
    double* C64 = B64 + eB * Bc;
    double* T64 = C64 + eC * Bc;
    float*  Z32 = (float*)(T64 + eT * Bc);
    float*  Qf  = Z32 + eZ * Bc;
    float* Df = (float*)B64;   // decoder fp32 aliases (encoder buffers dead)
    float* Tf = (float*)T64;
    float* Ef = (float*)A64;

    hipMemsetAsync(LS, 0, sizeof(double), stream);
    codenorm_kernel<<<8, 64, 0, stream>>>(codebook, CN);

    for (int c = 0; c < nChunks; c++) {
        const float* xc = x + (long)c * Bc * 3 * 65536;
        float* outc = out + (long)c * Bc * 3 * 65536;

        // ---- encoder (fp64 accumulate -> fp32 z) ----
        // enc1: 4x4 s2 3->64, 256->128, OUT_RELU. Cin=3=NCI: single round.
        conv_tiled<float,double,double,4,2,1,false,true,false,3,32>
            <<<Bc*8*8*2, 256, 0, stream>>>(
            xc, enc_w1, enc_b1, nullptr, A64, Bc, 3, 256, 256, 64, 128, 128);
        // enc2: 4x4 s2 64->128, 128->64, OUT_RELU. NCI=4: 16 rounds, 38KB LDS.
        conv_tiled<double,double,double,4,2,1,false,true,false,4,32>
            <<<Bc*4*4*4, 256, 0, stream>>>(
            A64, enc_w2, enc_b2, nullptr, B64, Bc, 64, 128, 128, 128, 64, 64);
        // enc3: 3x3 s1 128->128. NCI=8: 16 rounds.
        conv_tiled<double,double,double,3,1,1,false,false,false,8,32>
            <<<Bc*4*4*4, 256, 0, stream>>>(
            B64, enc_w3, enc_b3, nullptr, C64, Bc, 128, 64, 64, 128, 64, 64);
        for (int i = 0; i < 2; i++) {
            // res1: 3x3 128->32, IN_RELU. COB=16, NCI=8.
            conv_tiled<double,double,double,3,1,1,true,false,false,8,16>
                <<<Bc*4*4*2, 256, 0, stream>>>(
                C64, enc_rw1 + (long)i*32*128*9, enc_rb1 + i*32, nullptr, T64,
                Bc, 128, 64, 64, 32, 64, 64);
            // res2: 1x1 32->128, IN_RELU, +residual C64, in-place C64.
            conv_tiled<double,double,double,1,1,0,true,false,true,16,32>
                <<<Bc*4*4*4, 256, 0, stream>>>(
                T64, enc_rw2 + (long)i*128*32, enc_rb2 + i*128, C64, C64,
                Bc, 32, 64, 64, 128, 64, 64);
        }
        // pvq: 1x1 128->64, IN_RELU, fp32 store.
        conv_tiled<double,double,float,1,1,0,true,false,false,16,32>
            <<<Bc*4*4*2, 256, 0, stream>>>(
            C64, pvq_w, pvq_b, nullptr, Z32, Bc, 128, 64, 64, 64, 64, 64);

        // ---- VQ (np-exact fp32) ----
        vq_kernel<<<Bc * 16, 256, 0, stream>>>(Z32, codebook, CN, Qf, LS, Bc);

        // ---- decoder (fp32), fp32 output stores ----
        conv_tiled<float,float,float,3,1,1,false,false,false,16,32>
            <<<Bc*4*4*4, 256, 0, stream>>>(
            Qf, dec_w1, dec_b1, nullptr, Df, Bc, 64, 64, 64, 128, 64, 64);
        for (int i = 0; i < 2; i++) {
            conv_tiled<float,float,float,3,1,1,true,false,false,16,16>
                <<<Bc*4*4*2, 256, 0, stream>>>(
                Df, dec_rw1 + (long)i*32*128*9, dec_rb1 + i*32, nullptr, Tf,
                Bc, 128, 64, 64, 32, 64, 64);
            conv_tiled<float,float,float,1,1,0,true,false,true,16,32>
                <<<Bc*4*4*4, 256, 0, stream>>>(
                Tf, dec_rw2 + (long)i*128*32, dec_rb2 + i*128, Df, Df,
                Bc, 32, 64, 64, 128, 64, 64);
        }
        // dt1: deconv 128->64, 64->128, IN_RELU + OUT_RELU. NCI=16: 8 rounds.
        deconv_tiled<8,true,true,false,16><<<Bc*4*4*8, 256, 0, stream>>>(
            Df, dt1_w, dt1_b, Ef, Bc, 128, 64, 64, 64);
        // dt2: deconv 64->3, 128->256, tanh, writes final output. NCI=16.
        deconv_tiled<3,false,false,true,16><<<Bc*8*8*1, 256, 0, stream>>>(
            Ef, dt2_w, dt2_b, outc, Bc, 64, 128, 128, 3);
    }

    loss_final_kernel<<<1, 1, 0, stream>>>(LS, out + 6291456);
}